// Round 7
// baseline (857.580 us; speedup 1.0000x reference)
//
#include <hip/hip_runtime.h>
#include <hip/hip_bf16.h>
#include <stdint.h>

// FusedMoEBlock R6: both operands staged through LDS with coalesced loads.
// A: XOR-swizzled LDS tile (conflict-free ds_read_b128 fragments), dbuf.
// B: R5 pack-transpose LDS (LDP=68), dbuf, depth-2 reg sets.
// One raw barrier (lgkmcnt-only) per K-step; global loads fly across it.
// T=2048,H=2048,E=64,I=512,IS=1024,k<=8.
// d_out = [shared_out (T*H f32) | routed (T*H f32)].

#define H_DIM 2048
#define E_NUM 64
#define I_DIM 512
#define IS_DIM 1024
#define CAP 512
#define TOPK_MAX 8
#define BK 64
#define BM 128
#define LDP 68   // B LDS row stride (u16): 34 dwords == 2 mod 32 -> <=2-way

typedef float f32x4 __attribute__((ext_vector_type(4)));
typedef __bf16 bf16x8 __attribute__((ext_vector_type(8)));

__device__ __forceinline__ uint16_t f2bf(float f) {
  union { float f; uint32_t u; } v;
  v.f = f;
  uint32_t r = (v.u + 0x7FFFu + ((v.u >> 16) & 1u)) >> 16;  // RNE
  return (uint16_t)r;
}
__device__ __forceinline__ uint32_t pack2(float a, float b) {
  return (uint32_t)f2bf(a) | ((uint32_t)f2bf(b) << 16);
}
__device__ __forceinline__ float bf2f(uint16_t b) {
  union { uint32_t u; float f; } v;
  v.u = (uint32_t)b << 16;
  return v.f;
}

// barrier WITHOUT vmcnt drain: LDS ops complete, global loads stay in flight
#define BAR()                                              \
  do {                                                     \
    asm volatile("s_waitcnt lgkmcnt(0)" ::: "memory");     \
    __builtin_amdgcn_s_barrier();                          \
    asm volatile("" ::: "memory");                         \
  } while (0)

// ---------------- router: logits -> sigmoid -> top-k -> buckets; writes xb --
__global__ __launch_bounds__(256) void router_kernel(
    const float* __restrict__ x, const float* __restrict__ gw,
    const int* __restrict__ topk_ptr, int* __restrict__ cnt,
    int* __restrict__ bucket, float* __restrict__ bw,
    uint16_t* __restrict__ xb) {
  const int t = blockIdx.x;
  const int tid = threadIdx.x;
  __shared__ float xs[H_DIM];
  __shared__ float logits[E_NUM];
#pragma unroll
  for (int i = 0; i < 2; ++i) {
    int idx = tid + i * 256;
    *(float4*)(&xs[idx * 4]) = *(const float4*)(x + (size_t)t * H_DIM + idx * 4);
  }
  __syncthreads();
  {  // fused f32->bf16 conversion of this token's row
    const float* p = &xs[tid * 8];
    uint4 o;
    o.x = pack2(p[0], p[1]);
    o.y = pack2(p[2], p[3]);
    o.z = pack2(p[4], p[5]);
    o.w = pack2(p[6], p[7]);
    ((uint4*)(xb + (size_t)t * H_DIM))[tid] = o;
  }
  const int lane = tid & 63, wid = tid >> 6;
  float xr[32];
#pragma unroll
  for (int it = 0; it < 32; ++it) xr[it] = xs[lane + 64 * it];
  for (int eo = 0; eo < 16; ++eo) {
    int e = wid + eo * 4;
    const float* g = gw + (size_t)e * H_DIM;
    float acc = 0.f;
#pragma unroll
    for (int it = 0; it < 32; ++it) acc += xr[it] * g[lane + 64 * it];
#pragma unroll
    for (int off = 32; off; off >>= 1) acc += __shfl_xor(acc, off);
    if (lane == 0) logits[e] = acc;
  }
  __syncthreads();
  if (wid == 0) {
    int k = topk_ptr[0];
    if (k > TOPK_MAX) k = TOPK_MAX;
    // sigmoid; pre-topk normalize is scale-invariant -> skipped
    float v = 1.f / (1.f + expf(-logits[lane]));
    float s = 0.f, myw = 0.f;
    int mye = 0;
    for (int j = 0; j < k; ++j) {
      float m = v;
      int mi = lane;
#pragma unroll
      for (int off = 32; off; off >>= 1) {
        float ov = __shfl_xor(m, off);
        int oi = __shfl_xor(mi, off);
        if (ov > m || (ov == m && oi < mi)) { m = ov; mi = oi; }
      }
      if (lane == j) { myw = m; mye = mi; }
      if (lane == mi) v = -1e30f;
      s += m;
    }
    if (lane < k) {
      float w = myw / s;
      int pos = atomicAdd(&cnt[mye], 1);
      if (pos < CAP) {
        bucket[mye * CAP + pos] = t * 8 + lane;  // token*8 + choice slot
        bw[mye * CAP + pos] = w;
      }
    }
  }
}

// ---------------- gate+up GEMM + silu*mul -> act (bf16) ----------------
// BM=128, BK=64, 4 waves M-split (32 rows each). A+B LDS dbuf, 1 bar/step.
template <int BN, bool GATHER>
__global__ __launch_bounds__(256) void ffn_in(
    const uint16_t* __restrict__ xb, const float* __restrict__ Wg,
    const float* __restrict__ Wu, uint16_t* __restrict__ act,
    const int* __restrict__ cnt, const int* __restrict__ bucket,
    const int K, const int ldb) {
  constexpr int MF = 2;            // 16-row frags per wave
  constexpr int NF = BN / 16;      // 16-col frags per wave (full BN)
  constexpr int CG = BN / 4;       // B col groups
  constexpr int PG = 256 / CG;     // k-pairs per pass
  constexpr int PAIRS = 32 / PG;

  int e = 0, nt, mt0, mtE, n_e;
  const float *Bg, *Bu;
  uint16_t* actE;
  if constexpr (GATHER) {
    e = blockIdx.x;  // gridDim.x=64 -> same-e blocks on XCD e%8
    nt = blockIdx.y;
    n_e = min(cnt[e], CAP);
    mt0 = 0;
    mtE = (n_e + BM - 1) / BM;
    const size_t wo = (size_t)e * K * ldb;
    Bg = Wg + wo;
    Bu = Wu + wo;
    actE = act + (size_t)e * CAP * ldb;
  } else {
    mt0 = blockIdx.x;  // same-nt strip spread across XCDs
    nt = blockIdx.y;
    mtE = mt0 + 1;
    n_e = 1 << 30;
    Bg = Wg;
    Bu = Wu;
    actE = act;
  }

  __shared__ uint16_t As[2][BM][64];   // swizzled: off ^= (row&7)<<3 (u16)
  __shared__ uint16_t Bgs[2][BN][LDP];
  __shared__ uint16_t Bus[2][BN][LDP];

  const int tid = threadIdx.x;
  // A staging: 8 threads/row, 4 passes of 32 rows
  const int arow = tid >> 3, achk = (tid & 7) * 8;
  const int axor = achk ^ ((arow & 7) << 3);
  // B staging
  const int cg4 = (tid % CG) * 4, kp = tid / CG;
  const float* bgp = Bg + (size_t)(2 * kp) * ldb + nt * BN + cg4;
  const float* bup = Bu + (size_t)(2 * kp) * ldb + nt * BN + cg4;

  const int lane = tid & 63, wid = tid >> 6;
  const int fr = lane & 15, kg = lane >> 4;
  const int wrow = wid * 32;

  struct BSet { float4 g0[PAIRS], g1[PAIRS], u0[PAIRS], u1[PAIRS]; };
  BSet bs0, bs1;
  uint4 aval[4];
  const uint16_t* abase[4];

  auto issueB = [&](BSet& S, int kq) {
#pragma unroll
    for (int pp = 0; pp < PAIRS; ++pp) {
      const float* g = bgp + (size_t)(kq + 2 * pp * PG) * ldb;
      S.g0[pp] = *(const float4*)g;
      S.g1[pp] = *(const float4*)(g + ldb);
      const float* u = bup + (size_t)(kq + 2 * pp * PG) * ldb;
      S.u0[pp] = *(const float4*)u;
      S.u1[pp] = *(const float4*)(u + ldb);
    }
  };
  auto packB = [&](int buf, const BSet& S) {
#pragma unroll
    for (int pp = 0; pp < PAIRS; ++pp) {
      const int k2 = 2 * (kp + pp * PG);
      *(uint32_t*)(&Bgs[buf][cg4 + 0][k2]) = pack2(S.g0[pp].x, S.g1[pp].x);
      *(uint32_t*)(&Bgs[buf][cg4 + 1][k2]) = pack2(S.g0[pp].y, S.g1[pp].y);
      *(uint32_t*)(&Bgs[buf][cg4 + 2][k2]) = pack2(S.g0[pp].z, S.g1[pp].z);
      *(uint32_t*)(&Bgs[buf][cg4 + 3][k2]) = pack2(S.g0[pp].w, S.g1[pp].w);
      *(uint32_t*)(&Bus[buf][cg4 + 0][k2]) = pack2(S.u0[pp].x, S.u1[pp].x);
      *(uint32_t*)(&Bus[buf][cg4 + 1][k2]) = pack2(S.u0[pp].y, S.u1[pp].y);
      *(uint32_t*)(&Bus[buf][cg4 + 2][k2]) = pack2(S.u0[pp].z, S.u1[pp].z);
      *(uint32_t*)(&Bus[buf][cg4 + 3][k2]) = pack2(S.u0[pp].w, S.u1[pp].w);
    }
  };
  auto issueA = [&](int kq) {
#pragma unroll
    for (int p = 0; p < 4; ++p) aval[p] = *(const uint4*)(abase[p] + kq);
  };
  auto packA = [&](int buf) {
#pragma unroll
    for (int p = 0; p < 4; ++p)
      *(uint4*)(&As[buf][arow + p * 32][axor]) = aval[p];
  };

  f32x4 accg[MF][NF];
  f32x4 accu[MF][NF];

  auto mfmaStep = [&](int buf) {
#pragma unroll
    for (int sl = 0; sl < 2; ++sl) {
      bf16x8 af[MF];
#pragma unroll
      for (int mf = 0; mf < MF; ++mf) {
        const int row = wrow + mf * 16 + fr;
        const int off = (sl * 32 + kg * 8) ^ ((row & 7) << 3);
        af[mf] = __builtin_bit_cast(bf16x8, *(const uint4*)(&As[buf][row][off]));
      }
#pragma unroll
      for (int nf = 0; nf < NF; ++nf) {
        const bf16x8 bg = __builtin_bit_cast(
            bf16x8, *(const uint4*)(&Bgs[buf][nf * 16 + fr][kg * 8 + sl * 32]));
        const bf16x8 bu = __builtin_bit_cast(
            bf16x8, *(const uint4*)(&Bus[buf][nf * 16 + fr][kg * 8 + sl * 32]));
#pragma unroll
        for (int mf = 0; mf < MF; ++mf) {
          accg[mf][nf] = __builtin_amdgcn_mfma_f32_16x16x32_bf16(
              af[mf], bg, accg[mf][nf], 0, 0, 0);
          accu[mf][nf] = __builtin_amdgcn_mfma_f32_16x16x32_bf16(
              af[mf], bu, accu[mf][nf], 0, 0, 0);
        }
      }
    }
  };

  const int NS = K / BK;
  for (int mt = mt0; mt < mtE; ++mt) {
#pragma unroll
    for (int p = 0; p < 4; ++p) {
      const int slot = mt * BM + arow + p * 32;
      if constexpr (GATHER) {
        const int idx = slot < n_e ? slot : 0;
        abase[p] = xb + (size_t)(bucket[e * CAP + idx] >> 3) * K + achk;
      } else {
        abase[p] = xb + (size_t)slot * K + achk;
      }
    }
#pragma unroll
    for (int mf = 0; mf < MF; ++mf)
#pragma unroll
      for (int nf = 0; nf < NF; ++nf) {
        accg[mf][nf] = (f32x4){0.f, 0.f, 0.f, 0.f};
        accu[mf][nf] = (f32x4){0.f, 0.f, 0.f, 0.f};
      }

    // prologue
    issueB(bs0, 0);
    issueA(0);
    packB(0, bs0);
    packA(0);
    issueB(bs1, BK);
    issueA(BK);
    BAR();

#define GSTEP(S, SI, SP)                          \
    {                                             \
      const int cur = (S) & 1, nxt = cur ^ 1;     \
      if ((S) + 2 < NS) issueB(SI, ((S) + 2) * BK); \
      if ((S) + 1 < NS) { packB(nxt, SP); packA(nxt); } \
      if ((S) + 2 < NS) issueA(((S) + 2) * BK);   \
      mfmaStep(cur);                              \
      BAR();                                      \
    }
    for (int s = 0; s < NS; s += 2) {
      GSTEP(s, bs0, bs1);
      GSTEP(s + 1, bs1, bs0);
    }
#undef GSTEP

    const int col0 = nt * BN + fr;
#pragma unroll
    for (int mf = 0; mf < MF; ++mf)
#pragma unroll
      for (int rr = 0; rr < 4; ++rr) {
        const int slot = mt * BM + wrow + mf * 16 + kg * 4 + rr;
        if (slot < n_e) {
          const size_t ro = (size_t)slot * ldb + col0;
#pragma unroll
          for (int nf = 0; nf < NF; ++nf) {
            const float g = accg[mf][nf][rr], u = accu[mf][nf][rr];
            actE[ro + nf * 16] = f2bf(g / (1.f + expf(-g)) * u);
          }
        }
      }
  }
}

// ---------------- down GEMM; GATHER -> weighted bf16 rows into ybuf ---------
template <int BN, bool GATHER>
__global__ __launch_bounds__(256) void ffn_down(
    const uint16_t* __restrict__ act, const float* __restrict__ Wd,
    void* __restrict__ outp, const int* __restrict__ cnt,
    const int* __restrict__ bucket, const float* __restrict__ bw, const int K) {
  constexpr int MF = 2;
  constexpr int NF = BN / 16;
  constexpr int CG = BN / 4;
  constexpr int PG = 256 / CG;
  constexpr int PAIRS = 32 / PG;

  int e = 0, nt, mt0, mtE, n_e;
  const float* Bd;
  const uint16_t* actE;
  if constexpr (GATHER) {
    e = blockIdx.x;
    nt = blockIdx.y;
    n_e = min(cnt[e], CAP);
    mt0 = 0;
    mtE = (n_e + BM - 1) / BM;
    actE = act + (size_t)e * CAP * K;
    Bd = Wd + (size_t)e * K * H_DIM;
  } else {
    mt0 = blockIdx.x;
    nt = blockIdx.y;
    mtE = mt0 + 1;
    n_e = 1 << 30;
    actE = act;
    Bd = Wd;
  }

  __shared__ uint16_t As[2][BM][64];
  __shared__ uint16_t Bs[2][BN][LDP];

  const int tid = threadIdx.x;
  const int arow = tid >> 3, achk = (tid & 7) * 8;
  const int axor = achk ^ ((arow & 7) << 3);
  const int cg4 = (tid % CG) * 4, kp = tid / CG;
  const float* bdp = Bd + (size_t)(2 * kp) * H_DIM + nt * BN + cg4;

  const int lane = tid & 63, wid = tid >> 6;
  const int fr = lane & 15, kg = lane >> 4;
  const int wrow = wid * 32;

  struct DSet { float4 d0[PAIRS], d1[PAIRS]; };
  DSet ds0, ds1;
  uint4 aval[4];
  const uint16_t* abase[4];

  auto issueB = [&](DSet& S, int kq) {
#pragma unroll
    for (int pp = 0; pp < PAIRS; ++pp) {
      const float* d = bdp + (size_t)(kq + 2 * pp * PG) * H_DIM;
      S.d0[pp] = *(const float4*)d;
      S.d1[pp] = *(const float4*)(d + H_DIM);
    }
  };
  auto packB = [&](int buf, const DSet& S) {
#pragma unroll
    for (int pp = 0; pp < PAIRS; ++pp) {
      const int k2 = 2 * (kp + pp * PG);
      *(uint32_t*)(&Bs[buf][cg4 + 0][k2]) = pack2(S.d0[pp].x, S.d1[pp].x);
      *(uint32_t*)(&Bs[buf][cg4 + 1][k2]) = pack2(S.d0[pp].y, S.d1[pp].y);
      *(uint32_t*)(&Bs[buf][cg4 + 2][k2]) = pack2(S.d0[pp].z, S.d1[pp].z);
      *(uint32_t*)(&Bs[buf][cg4 + 3][k2]) = pack2(S.d0[pp].w, S.d1[pp].w);
    }
  };
  auto issueA = [&](int kq) {
#pragma unroll
    for (int p = 0; p < 4; ++p) aval[p] = *(const uint4*)(abase[p] + kq);
  };
  auto packA = [&](int buf) {
#pragma unroll
    for (int p = 0; p < 4; ++p)
      *(uint4*)(&As[buf][arow + p * 32][axor]) = aval[p];
  };

  f32x4 acc[MF][NF];

  auto mfmaStep = [&](int buf) {
#pragma unroll
    for (int sl = 0; sl < 2; ++sl) {
      bf16x8 af[MF];
#pragma unroll
      for (int mf = 0; mf < MF; ++mf) {
        const int row = wrow + mf * 16 + fr;
        const int off = (sl * 32 + kg * 8) ^ ((row & 7) << 3);
        af[mf] = __builtin_bit_cast(bf16x8, *(const uint4*)(&As[buf][row][off]));
      }
#pragma unroll
      for (int nf = 0; nf < NF; ++nf) {
        const bf16x8 bf_ = __builtin_bit_cast(
            bf16x8, *(const uint4*)(&Bs[buf][nf * 16 + fr][kg * 8 + sl * 32]));
#pragma unroll
        for (int mf = 0; mf < MF; ++mf)
          acc[mf][nf] = __builtin_amdgcn_mfma_f32_16x16x32_bf16(
              af[mf], bf_, acc[mf][nf], 0, 0, 0);
      }
    }
  };

  const int NS = K / BK;
  for (int mt = mt0; mt < mtE; ++mt) {
#pragma unroll
    for (int p = 0; p < 4; ++p) {
      const int slot = mt * BM + arow + p * 32;
      const int idx = slot < n_e ? slot : 0;
      abase[p] = actE + (size_t)idx * K + achk;
    }
#pragma unroll
    for (int mf = 0; mf < MF; ++mf)
#pragma unroll
      for (int nf = 0; nf < NF; ++nf) acc[mf][nf] = (f32x4){0.f, 0.f, 0.f, 0.f};

    issueB(ds0, 0);
    issueA(0);
    packB(0, ds0);
    packA(0);
    issueB(ds1, BK);
    issueA(BK);
    BAR();

#define DSTEP(S, SI, SP)                          \
    {                                             \
      const int cur = (S) & 1, nxt = cur ^ 1;     \
      if ((S) + 2 < NS) issueB(SI, ((S) + 2) * BK); \
      if ((S) + 1 < NS) { packB(nxt, SP); packA(nxt); } \
      if ((S) + 2 < NS) issueA(((S) + 2) * BK);   \
      mfmaStep(cur);                              \
      BAR();                                      \
    }
    for (int s = 0; s < NS; s += 2) {
      DSTEP(s, ds0, ds1);
      DSTEP(s + 1, ds1, ds0);
    }
#undef DSTEP

    const int col0 = nt * BN + fr;
#pragma unroll
    for (int mf = 0; mf < MF; ++mf)
#pragma unroll
      for (int rr = 0; rr < 4; ++rr) {
        const int slot = mt * BM + wrow + mf * 16 + kg * 4 + rr;
        if constexpr (GATHER) {
          if (slot < n_e) {
            const int bv = bucket[e * CAP + slot];
            const float w = bw[e * CAP + slot];
            uint16_t* yb = (uint16_t*)outp + (size_t)bv * H_DIM + col0;
#pragma unroll
            for (int nf = 0; nf < NF; ++nf)
              yb[nf * 16] = f2bf(w * acc[mf][nf][rr]);
          }
        } else {
          float* op = (float*)outp + (size_t)slot * H_DIM + col0;
#pragma unroll
          for (int nf = 0; nf < NF; ++nf) op[nf * 16] = acc[mf][nf][rr];
        }
      }
  }
}

// ---------------- combine: routed[t] = sum_{j<k} ybuf[t*8+j] ----------------
__global__ __launch_bounds__(256) void gather_kernel(
    const uint16_t* __restrict__ ybuf, const int* __restrict__ topk_ptr,
    float* __restrict__ routed) {
  const int t = blockIdx.x;
  const int tid = threadIdx.x;
  int k = topk_ptr[0];
  if (k > TOPK_MAX) k = TOPK_MAX;
  float acc[8] = {};
  const uint16_t* base = ybuf + (size_t)t * 8 * H_DIM + tid * 8;
  for (int j = 0; j < k; ++j) {
    uint4 v = *(const uint4*)(base + (size_t)j * H_DIM);
    const uint16_t* h = (const uint16_t*)&v;
#pragma unroll
    for (int i = 0; i < 8; ++i) acc[i] += bf2f(h[i]);
  }
  float4 o0 = make_float4(acc[0], acc[1], acc[2], acc[3]);
  float4 o1 = make_float4(acc[4], acc[5], acc[6], acc[7]);
  float* op = routed + (size_t)t * H_DIM + tid * 8;
  *(float4*)op = o0;
  *(float4*)(op + 4) = o1;
}

extern "C" void kernel_launch(void* const* d_in, const int* in_sizes, int n_in,
                              void* d_out, int out_size, void* d_ws, size_t ws_size,
                              hipStream_t stream) {
  const float* x = (const float*)d_in[0];
  const float* gw = (const float*)d_in[1];
  const float* w_gate = (const float*)d_in[2];
  const float* w_up = (const float*)d_in[3];
  const float* w_down = (const float*)d_in[4];
  const float* sw_gate = (const float*)d_in[5];
  const float* sw_up = (const float*)d_in[6];
  const float* sw_down = (const float*)d_in[7];
  const int* topk = (const int*)d_in[8];
  const int T = in_sizes[0] / H_DIM;  // 2048

  float* shared_out = (float*)d_out;
  float* routed = shared_out + (size_t)T * H_DIM;

  char* ws = (char*)d_ws;
  size_t off = 0;
  auto take = [&](size_t b) {
    char* p = ws + off;
    off += (b + 255) & ~(size_t)255;
    return p;
  };
  uint16_t* xb = (uint16_t*)take((size_t)T * H_DIM * 2);              // 8.4 MB
  int* cnt = (int*)take(E_NUM * 4);
  int* bucket = (int*)take((size_t)E_NUM * CAP * 4);
  float* bw = (float*)take((size_t)E_NUM * CAP * 4);
  uint16_t* act = (uint16_t*)take((size_t)E_NUM * CAP * I_DIM * 2);   // 33.5 MB
  uint16_t* s_act = (uint16_t*)take((size_t)T * IS_DIM * 2);          // 4.2 MB
  uint16_t* ybuf = (uint16_t*)take((size_t)T * 8 * H_DIM * 2);        // 67 MB

  hipMemsetAsync(cnt, 0, E_NUM * 4, stream);

  router_kernel<<<T, 256, 0, stream>>>(x, gw, topk, cnt, bucket, bw, xb);

  // grouped gate+up: (e, nt) BN=64 -> 512 blocks, XCD-pinned per expert
  ffn_in<64, true><<<dim3(E_NUM, I_DIM / 64), 256, 0, stream>>>(
      xb, w_gate, w_up, act, cnt, bucket, H_DIM, I_DIM);
  // grouped down: (e, nt) BN=64 -> weighted bf16 rows in ybuf
  ffn_down<64, true><<<dim3(E_NUM, H_DIM / 64), 256, 0, stream>>>(
      act, w_down, (void*)ybuf, cnt, bucket, bw, I_DIM);
  // combine routed
  gather_kernel<<<T, 256, 0, stream>>>(ybuf, topk, routed);
  // shared gate+up: (mt, nt)
  ffn_in<64, false><<<dim3(T / BM, IS_DIM / 64), 256, 0, stream>>>(
      xb, sw_gate, sw_up, s_act, nullptr, nullptr, H_DIM, IS_DIM);
  // shared down: (mt, nt) -> shared_out (f32)
  ffn_down<64, false><<<dim3(T / BM, H_DIM / 64), 256, 0, stream>>>(
      s_act, sw_down, (void*)shared_out, nullptr, nullptr, nullptr, IS_DIM);
}

// Round 8
// 440.522 us; speedup vs baseline: 1.9467x; 1.9467x over previous
//
#include <hip/hip_runtime.h>
#include <hip/hip_bf16.h>
#include <stdint.h>

// FusedMoEBlock R7: k-blocked token layouts -> contiguous 1KB A-fragment
// loads straight from L2 (no A LDS, no bucket indirection in GEMMs).
// B path: R5 reg->pack-transpose LDS dbuf, raw lgkm barrier (loads fly).
// Layouts: xbK[kblk][t][32], xe[e][kblk][slot][32], act[e][kblk][slot][32],
//          s_act[kblk][t][32]  (kblk = k/32, chunk of 32 bf16 = 64B).
// T=2048,H=2048,E=64,I=512,IS=1024,k<=8.
// d_out = [shared_out (T*H f32) | routed (T*H f32)].

#define H_DIM 2048
#define E_NUM 64
#define I_DIM 512
#define IS_DIM 1024
#define CAPR 288     // padded slots/expert (mean 192, sigma 13 -> 7.2 sigma)
#define TOPK_MAX 8
#define BK 64
#define LDP 68       // B LDS row stride (u16): 34 dwords == 2 mod 32

typedef float f32x4 __attribute__((ext_vector_type(4)));
typedef __bf16 bf16x8 __attribute__((ext_vector_type(8)));

__device__ __forceinline__ uint16_t f2bf(float f) {
  union { float f; uint32_t u; } v;
  v.f = f;
  uint32_t r = (v.u + 0x7FFFu + ((v.u >> 16) & 1u)) >> 16;  // RNE
  return (uint16_t)r;
}
__device__ __forceinline__ uint32_t pack2(float a, float b) {
  return (uint32_t)f2bf(a) | ((uint32_t)f2bf(b) << 16);
}
__device__ __forceinline__ float bf2f(uint16_t b) {
  union { uint32_t u; float f; } v;
  v.u = (uint32_t)b << 16;
  return v.f;
}

// barrier WITHOUT vmcnt drain: LDS ops complete, global loads stay in flight
#define BAR()                                              \
  do {                                                     \
    asm volatile("s_waitcnt lgkmcnt(0)" ::: "memory");     \
    __builtin_amdgcn_s_barrier();                          \
    asm volatile("" ::: "memory");                         \
  } while (0)

// ---------------- router: logits/top-k/buckets; writes xbK (k-blocked) -----
__global__ __launch_bounds__(256) void router_kernel(
    const float* __restrict__ x, const float* __restrict__ gw,
    const int* __restrict__ topk_ptr, int* __restrict__ cnt,
    int* __restrict__ bucket, float* __restrict__ bw,
    uint16_t* __restrict__ xbK, const int T) {
  const int t = blockIdx.x;
  const int tid = threadIdx.x;
  __shared__ float xs[H_DIM];
  __shared__ float logits[E_NUM];
#pragma unroll
  for (int i = 0; i < 2; ++i) {
    int idx = tid + i * 256;
    *(float4*)(&xs[idx * 4]) = *(const float4*)(x + (size_t)t * H_DIM + idx * 4);
  }
  __syncthreads();
  {  // f32 -> bf16, k-blocked: xbK[tid>>2][t][ (tid&3)*8 .. +7 ]
    const float* p = &xs[tid * 8];
    uint4 o;
    o.x = pack2(p[0], p[1]);
    o.y = pack2(p[2], p[3]);
    o.z = pack2(p[4], p[5]);
    o.w = pack2(p[6], p[7]);
    *(uint4*)(xbK + (size_t)(tid >> 2) * T * 32 + (size_t)t * 32 +
              (tid & 3) * 8) = o;
  }
  const int lane = tid & 63, wid = tid >> 6;
  float xr[32];
#pragma unroll
  for (int it = 0; it < 32; ++it) xr[it] = xs[lane + 64 * it];
  for (int eo = 0; eo < 16; ++eo) {
    int e = wid + eo * 4;
    const float* g = gw + (size_t)e * H_DIM;
    float acc = 0.f;
#pragma unroll
    for (int it = 0; it < 32; ++it) acc += xr[it] * g[lane + 64 * it];
#pragma unroll
    for (int off = 32; off; off >>= 1) acc += __shfl_xor(acc, off);
    if (lane == 0) logits[e] = acc;
  }
  __syncthreads();
  if (wid == 0) {
    int k = topk_ptr[0];
    if (k > TOPK_MAX) k = TOPK_MAX;
    // sigmoid; pre-topk normalize is scale-invariant -> skipped
    float v = 1.f / (1.f + expf(-logits[lane]));
    float s = 0.f, myw = 0.f;
    int mye = 0;
    for (int j = 0; j < k; ++j) {
      float m = v;
      int mi = lane;
#pragma unroll
      for (int off = 32; off; off >>= 1) {
        float ov = __shfl_xor(m, off);
        int oi = __shfl_xor(mi, off);
        if (ov > m || (ov == m && oi < mi)) { m = ov; mi = oi; }
      }
      if (lane == j) { myw = m; mye = mi; }
      if (lane == mi) v = -1e30f;
      s += m;
    }
    if (lane < k) {
      float w = myw / s;
      int pos = atomicAdd(&cnt[mye], 1);
      if (pos < CAPR) {
        bucket[mye * CAPR + pos] = t * 8 + lane;  // token*8 + choice slot
        bw[mye * CAPR + pos] = w;
      }
    }
  }
}

// ---------------- gather: xe[e][kblk][slot][32] = xbK[kblk][token][32] -----
// block: (e, kgrp + 16*sgrp); thread: slot = sgrp*64 + (tid&63),
// kblk = kgrp*4 + (tid>>6). Writes coalesced (consecutive slots).
__global__ __launch_bounds__(256) void gather_xe(
    const uint16_t* __restrict__ xbK, const int* __restrict__ cnt,
    const int* __restrict__ bucket, uint16_t* __restrict__ xe, const int T) {
  const int e = blockIdx.x;
  const int kgrp = blockIdx.y & 15, sgrp = blockIdx.y >> 4;
  const int tid = threadIdx.x;
  const int slot = sgrp * 64 + (tid & 63);
  const int kblk = kgrp * 4 + (tid >> 6);
  const int n_e = min(cnt[e], CAPR);
  if (slot >= n_e) return;
  const int t = bucket[e * CAPR + slot] >> 3;
  const uint4* src = (const uint4*)(xbK + (size_t)kblk * T * 32 + (size_t)t * 32);
  uint4* dst = (uint4*)(xe + (size_t)e * (64 * CAPR * 32) +
                        (size_t)kblk * (CAPR * 32) + (size_t)slot * 32);
#pragma unroll
  for (int j = 0; j < 4; ++j) dst[j] = src[j];
}

// ---------------- gate+up GEMM + silu*mul -> act (bf16, k-blocked) ---------
// BN=32. 4 waves M-split. A: contiguous 1KB fragment loads from k-blocked AE.
// B: f32 pack-transpose LDS dbuf, depth-1 reg prefetch, raw lgkm barrier.
template <int BM, bool GATHER>
__global__ __launch_bounds__(256) void ffn_in(
    const uint16_t* __restrict__ A0, const float* __restrict__ Wg,
    const float* __restrict__ Wu, uint16_t* __restrict__ actO,
    const int* __restrict__ cnt, const int K, const int ldb, const int SLOTS) {
  constexpr int BN = 32;
  constexpr int MF = BM / 64;   // 16-row frags per wave (wave owns BM/4 rows)
  constexpr int NF = 2;

  int e = 0, nt, mt0, mtE, n_e;
  const float *Bg, *Bu;
  const uint16_t* AE;
  uint16_t* outE;
  if constexpr (GATHER) {
    e = blockIdx.x;  // gridDim.x=64 -> same-e blocks on XCD e%8
    nt = blockIdx.y;
    n_e = min(cnt[e], CAPR);
    mt0 = 0;
    mtE = (n_e + BM - 1) / BM;
    const size_t wo = (size_t)e * K * ldb;
    Bg = Wg + wo;
    Bu = Wu + wo;
    AE = A0 + (size_t)e * (64 * CAPR * 32);
    outE = actO + (size_t)e * ((I_DIM / 32) * CAPR * 32);
  } else {
    nt = blockIdx.x;  // same-strip blocks share XCD nt%8
    mt0 = blockIdx.y;
    mtE = mt0 + 1;
    n_e = 1 << 30;
    Bg = Wg;
    Bu = Wu;
    AE = A0;
    outE = actO;
  }
  if (mt0 * BM >= n_e) return;

  __shared__ uint16_t Bgs[2][BN][LDP];
  __shared__ uint16_t Bus[2][BN][LDP];

  const int tid = threadIdx.x;
  const int cg4 = (tid & 7) * 4, kp = tid >> 3;  // CG=8, kp 0..31
  const float* bgp = Bg + (size_t)(2 * kp) * ldb + nt * BN + cg4;
  const float* bup = Bu + (size_t)(2 * kp) * ldb + nt * BN + cg4;

  const int lane = tid & 63, wid = tid >> 6;
  const int fr = lane & 15, kg = lane >> 4;
  const int wrow = wid * (BM / 4);
  const size_t ldA = (size_t)SLOTS * 32;  // u16 per kblk

  float4 g0, g1, u0, u1;
  const int NS = K / BK;

  for (int mt = mt0; mt < mtE; ++mt) {
    const uint16_t* ab[MF];
#pragma unroll
    for (int mf = 0; mf < MF; ++mf)
      ab[mf] = AE + (size_t)(mt * BM + wrow + mf * 16 + fr) * 32 + kg * 8;

    f32x4 accg[MF][NF] = {};
    f32x4 accu[MF][NF] = {};

    // prologue: load+pack B(0); issue B(1)
    g0 = *(const float4*)bgp;
    g1 = *(const float4*)(bgp + ldb);
    u0 = *(const float4*)bup;
    u1 = *(const float4*)(bup + ldb);
    {
      const int k2 = 2 * kp;
      *(uint32_t*)(&Bgs[0][cg4 + 0][k2]) = pack2(g0.x, g1.x);
      *(uint32_t*)(&Bgs[0][cg4 + 1][k2]) = pack2(g0.y, g1.y);
      *(uint32_t*)(&Bgs[0][cg4 + 2][k2]) = pack2(g0.z, g1.z);
      *(uint32_t*)(&Bgs[0][cg4 + 3][k2]) = pack2(g0.w, g1.w);
      *(uint32_t*)(&Bus[0][cg4 + 0][k2]) = pack2(u0.x, u1.x);
      *(uint32_t*)(&Bus[0][cg4 + 1][k2]) = pack2(u0.y, u1.y);
      *(uint32_t*)(&Bus[0][cg4 + 2][k2]) = pack2(u0.z, u1.z);
      *(uint32_t*)(&Bus[0][cg4 + 3][k2]) = pack2(u0.w, u1.w);
    }
    if (NS > 1) {
      const float* g = bgp + (size_t)BK * ldb;
      g0 = *(const float4*)g;
      g1 = *(const float4*)(g + ldb);
      const float* u = bup + (size_t)BK * ldb;
      u0 = *(const float4*)u;
      u1 = *(const float4*)(u + ldb);
    }
    BAR();

    int b = 0;
    for (int s = 0; s < NS; ++s) {
      // (1) A fragments for this step: two contiguous 1KB wave-loads per mf
      uint4 a[MF][2];
#pragma unroll
      for (int mf = 0; mf < MF; ++mf)
#pragma unroll
        for (int sl = 0; sl < 2; ++sl)
          a[mf][sl] = *(const uint4*)(ab[mf] + (size_t)(2 * s + sl) * ldA);
      // (2) pack B(s+1) -> buf b^1 (auto-waits its loads; A stays in flight)
      if (s + 1 < NS) {
        const int k2 = 2 * kp;
        *(uint32_t*)(&Bgs[b ^ 1][cg4 + 0][k2]) = pack2(g0.x, g1.x);
        *(uint32_t*)(&Bgs[b ^ 1][cg4 + 1][k2]) = pack2(g0.y, g1.y);
        *(uint32_t*)(&Bgs[b ^ 1][cg4 + 2][k2]) = pack2(g0.z, g1.z);
        *(uint32_t*)(&Bgs[b ^ 1][cg4 + 3][k2]) = pack2(g0.w, g1.w);
        *(uint32_t*)(&Bus[b ^ 1][cg4 + 0][k2]) = pack2(u0.x, u1.x);
        *(uint32_t*)(&Bus[b ^ 1][cg4 + 1][k2]) = pack2(u0.y, u1.y);
        *(uint32_t*)(&Bus[b ^ 1][cg4 + 2][k2]) = pack2(u0.z, u1.z);
        *(uint32_t*)(&Bus[b ^ 1][cg4 + 3][k2]) = pack2(u0.w, u1.w);
      }
      // (3) issue B(s+2) (stays in flight across the barrier)
      if (s + 2 < NS) {
        const float* g = bgp + (size_t)((s + 2) * BK) * ldb;
        g0 = *(const float4*)g;
        g1 = *(const float4*)(g + ldb);
        const float* u = bup + (size_t)((s + 2) * BK) * ldb;
        u0 = *(const float4*)u;
        u1 = *(const float4*)(u + ldb);
      }
      // (4) MFMA
#pragma unroll
      for (int sl = 0; sl < 2; ++sl)
#pragma unroll
        for (int nf = 0; nf < NF; ++nf) {
          const bf16x8 bg = __builtin_bit_cast(
              bf16x8, *(const uint4*)(&Bgs[b][nf * 16 + fr][kg * 8 + sl * 32]));
          const bf16x8 bu = __builtin_bit_cast(
              bf16x8, *(const uint4*)(&Bus[b][nf * 16 + fr][kg * 8 + sl * 32]));
#pragma unroll
          for (int mf = 0; mf < MF; ++mf) {
            const bf16x8 af = __builtin_bit_cast(bf16x8, a[mf][sl]);
            accg[mf][nf] = __builtin_amdgcn_mfma_f32_16x16x32_bf16(
                af, bg, accg[mf][nf], 0, 0, 0);
            accu[mf][nf] = __builtin_amdgcn_mfma_f32_16x16x32_bf16(
                af, bu, accu[mf][nf], 0, 0, 0);
          }
        }
      BAR();
      b ^= 1;
    }

    // epilogue: k-blocked act write: outE[nt][slot][nf*16+fr]
#pragma unroll
    for (int mf = 0; mf < MF; ++mf)
#pragma unroll
      for (int rr = 0; rr < 4; ++rr) {
        const int slot = mt * BM + wrow + mf * 16 + kg * 4 + rr;
        if (slot < n_e) {
          uint16_t* op = outE + (size_t)nt * ldA + (size_t)slot * 32 + fr;
#pragma unroll
          for (int nf = 0; nf < NF; ++nf) {
            const float g = accg[mf][nf][rr], u = accu[mf][nf][rr];
            op[nf * 16] = f2bf(g / (1.f + expf(-g)) * u);
          }
        }
      }
  }
}

// ---------------- down GEMM; GATHER -> weighted bf16 rows into ybuf --------
template <int BM, bool GATHER>
__global__ __launch_bounds__(256) void ffn_down(
    const uint16_t* __restrict__ A0, const float* __restrict__ Wd,
    void* __restrict__ outp, const int* __restrict__ cnt,
    const int* __restrict__ bucket, const float* __restrict__ bw,
    const int K, const int SLOTS) {
  constexpr int BN = 64;
  constexpr int MF = BM / 64;
  constexpr int NF = 4;

  int e = 0, nt, mt0, mtE, n_e;
  const float* Bd;
  const uint16_t* AE;
  if constexpr (GATHER) {
    e = blockIdx.x;
    nt = blockIdx.y;
    n_e = min(cnt[e], CAPR);
    mt0 = 0;
    mtE = (n_e + BM - 1) / BM;
    AE = A0 + (size_t)e * ((I_DIM / 32) * CAPR * 32);
    Bd = Wd + (size_t)e * K * H_DIM;
  } else {
    nt = blockIdx.x;
    mt0 = blockIdx.y;
    mtE = mt0 + 1;
    n_e = 1 << 30;
    AE = A0;
    Bd = Wd;
  }
  if (mt0 * BM >= n_e) return;

  __shared__ uint16_t Bs[2][BN][LDP];

  const int tid = threadIdx.x;
  const int cg4 = (tid & 15) * 4, kp = tid >> 4;  // CG=16, kp 0..15, PAIRS=2
  const float* bdp = Bd + (size_t)(2 * kp) * H_DIM + nt * BN + cg4;

  const int lane = tid & 63, wid = tid >> 6;
  const int fr = lane & 15, kg = lane >> 4;
  const int wrow = wid * (BM / 4);
  const size_t ldA = (size_t)SLOTS * 32;

  float4 d0[2], d1[2];
  const int NS = K / BK;

  for (int mt = mt0; mt < mtE; ++mt) {
    const uint16_t* ab[MF];
#pragma unroll
    for (int mf = 0; mf < MF; ++mf)
      ab[mf] = AE + (size_t)(mt * BM + wrow + mf * 16 + fr) * 32 + kg * 8;

    f32x4 acc[MF][NF] = {};

#pragma unroll
    for (int pp = 0; pp < 2; ++pp) {
      const float* d = bdp + (size_t)(2 * pp * 16) * H_DIM;
      d0[pp] = *(const float4*)d;
      d1[pp] = *(const float4*)(d + H_DIM);
    }
#pragma unroll
    for (int pp = 0; pp < 2; ++pp) {
      const int k2 = 2 * (kp + pp * 16);
      *(uint32_t*)(&Bs[0][cg4 + 0][k2]) = pack2(d0[pp].x, d1[pp].x);
      *(uint32_t*)(&Bs[0][cg4 + 1][k2]) = pack2(d0[pp].y, d1[pp].y);
      *(uint32_t*)(&Bs[0][cg4 + 2][k2]) = pack2(d0[pp].z, d1[pp].z);
      *(uint32_t*)(&Bs[0][cg4 + 3][k2]) = pack2(d0[pp].w, d1[pp].w);
    }
    if (NS > 1) {
#pragma unroll
      for (int pp = 0; pp < 2; ++pp) {
        const float* d = bdp + (size_t)(BK + 2 * pp * 16) * H_DIM;
        d0[pp] = *(const float4*)d;
        d1[pp] = *(const float4*)(d + H_DIM);
      }
    }
    BAR();

    int b = 0;
    for (int s = 0; s < NS; ++s) {
      uint4 a[MF][2];
#pragma unroll
      for (int mf = 0; mf < MF; ++mf)
#pragma unroll
        for (int sl = 0; sl < 2; ++sl)
          a[mf][sl] = *(const uint4*)(ab[mf] + (size_t)(2 * s + sl) * ldA);
      if (s + 1 < NS) {
#pragma unroll
        for (int pp = 0; pp < 2; ++pp) {
          const int k2 = 2 * (kp + pp * 16);
          *(uint32_t*)(&Bs[b ^ 1][cg4 + 0][k2]) = pack2(d0[pp].x, d1[pp].x);
          *(uint32_t*)(&Bs[b ^ 1][cg4 + 1][k2]) = pack2(d0[pp].y, d1[pp].y);
          *(uint32_t*)(&Bs[b ^ 1][cg4 + 2][k2]) = pack2(d0[pp].z, d1[pp].z);
          *(uint32_t*)(&Bs[b ^ 1][cg4 + 3][k2]) = pack2(d0[pp].w, d1[pp].w);
        }
      }
      if (s + 2 < NS) {
#pragma unroll
        for (int pp = 0; pp < 2; ++pp) {
          const float* d = bdp + (size_t)((s + 2) * BK + 2 * pp * 16) * H_DIM;
          d0[pp] = *(const float4*)d;
          d1[pp] = *(const float4*)(d + H_DIM);
        }
      }
#pragma unroll
      for (int sl = 0; sl < 2; ++sl)
#pragma unroll
        for (int nf = 0; nf < NF; ++nf) {
          const bf16x8 bf_ = __builtin_bit_cast(
              bf16x8, *(const uint4*)(&Bs[b][nf * 16 + fr][kg * 8 + sl * 32]));
#pragma unroll
          for (int mf = 0; mf < MF; ++mf) {
            const bf16x8 af = __builtin_bit_cast(bf16x8, a[mf][sl]);
            acc[mf][nf] = __builtin_amdgcn_mfma_f32_16x16x32_bf16(
                af, bf_, acc[mf][nf], 0, 0, 0);
          }
        }
      BAR();
      b ^= 1;
    }

    const int col0 = nt * BN + fr;
#pragma unroll
    for (int mf = 0; mf < MF; ++mf)
#pragma unroll
      for (int rr = 0; rr < 4; ++rr) {
        const int slot = mt * BM + wrow + mf * 16 + kg * 4 + rr;
        if constexpr (GATHER) {
          if (slot < n_e) {
            const int bv = bucket[e * CAPR + slot];
            const float w = bw[e * CAPR + slot];
            uint16_t* yb = (uint16_t*)outp + (size_t)bv * H_DIM + col0;
#pragma unroll
            for (int nf = 0; nf < NF; ++nf)
              yb[nf * 16] = f2bf(w * acc[mf][nf][rr]);
          }
        } else {
          float* op = (float*)outp + (size_t)slot * H_DIM + col0;
#pragma unroll
          for (int nf = 0; nf < NF; ++nf) op[nf * 16] = acc[mf][nf][rr];
        }
      }
  }
}

// ---------------- combine: routed[t] = sum_{j<k} ybuf[t*8+j] ----------------
__global__ __launch_bounds__(256) void combine_kernel(
    const uint16_t* __restrict__ ybuf, const int* __restrict__ topk_ptr,
    float* __restrict__ routed) {
  const int t = blockIdx.x;
  const int tid = threadIdx.x;
  int k = topk_ptr[0];
  if (k > TOPK_MAX) k = TOPK_MAX;
  float acc[8] = {};
  const uint16_t* base = ybuf + (size_t)t * 8 * H_DIM + tid * 8;
  for (int j = 0; j < k; ++j) {
    uint4 v = *(const uint4*)(base + (size_t)j * H_DIM);
    const uint16_t* h = (const uint16_t*)&v;
#pragma unroll
    for (int i = 0; i < 8; ++i) acc[i] += bf2f(h[i]);
  }
  float* op = routed + (size_t)t * H_DIM + tid * 8;
  *(float4*)op = make_float4(acc[0], acc[1], acc[2], acc[3]);
  *(float4*)(op + 4) = make_float4(acc[4], acc[5], acc[6], acc[7]);
}

extern "C" void kernel_launch(void* const* d_in, const int* in_sizes, int n_in,
                              void* d_out, int out_size, void* d_ws, size_t ws_size,
                              hipStream_t stream) {
  const float* x = (const float*)d_in[0];
  const float* gw = (const float*)d_in[1];
  const float* w_gate = (const float*)d_in[2];
  const float* w_up = (const float*)d_in[3];
  const float* w_down = (const float*)d_in[4];
  const float* sw_gate = (const float*)d_in[5];
  const float* sw_up = (const float*)d_in[6];
  const float* sw_down = (const float*)d_in[7];
  const int* topk = (const int*)d_in[8];
  const int T = in_sizes[0] / H_DIM;  // 2048

  float* shared_out = (float*)d_out;
  float* routed = shared_out + (size_t)T * H_DIM;

  char* ws = (char*)d_ws;
  size_t off = 0;
  auto take = [&](size_t b) {
    char* p = ws + off;
    off += (b + 255) & ~(size_t)255;
    return p;
  };
  uint16_t* xbK = (uint16_t*)take((size_t)T * H_DIM * 2);                // 8.4 MB
  int* cnt = (int*)take(E_NUM * 4);
  int* bucket = (int*)take((size_t)E_NUM * CAPR * 4);
  float* bw = (float*)take((size_t)E_NUM * CAPR * 4);
  uint16_t* xe = (uint16_t*)take((size_t)E_NUM * 64 * CAPR * 32 * 2 + 65536);   // 75.5 MB
  uint16_t* act = (uint16_t*)take((size_t)E_NUM * 16 * CAPR * 32 * 2 + 65536);  // 18.9 MB
  uint16_t* s_act = (uint16_t*)take((size_t)(IS_DIM / 32) * T * 32 * 2);        // 4.2 MB
  uint16_t* ybuf = (uint16_t*)take((size_t)T * 8 * H_DIM * 2);                  // 67 MB

  hipMemsetAsync(cnt, 0, E_NUM * 4, stream);

  router_kernel<<<T, 256, 0, stream>>>(x, gw, topk, cnt, bucket, bw, xbK, T);
  gather_xe<<<dim3(E_NUM, 16 * ((CAPR + 63) / 64)), 256, 0, stream>>>(
      xbK, cnt, bucket, xe, T);

  // grouped gate+up: BM=256 BN=32, grid (e, nt)
  ffn_in<256, true><<<dim3(E_NUM, I_DIM / 32), 256, 0, stream>>>(
      xe, w_gate, w_up, act, cnt, H_DIM, I_DIM, CAPR);
  // grouped down: BM=256 BN=64 -> weighted bf16 rows in ybuf
  ffn_down<256, true><<<dim3(E_NUM, H_DIM / 64), 256, 0, stream>>>(
      act, w_down, (void*)ybuf, cnt, bucket, bw, I_DIM, CAPR);
  // combine routed
  combine_kernel<<<T, 256, 0, stream>>>(ybuf, topk, routed);
  // shared gate+up: BM=128 BN=32, grid (nt, mt)
  ffn_in<128, false><<<dim3(IS_DIM / 32, T / 128), 256, 0, stream>>>(
      xbK, sw_gate, sw_up, s_act, nullptr, H_DIM, IS_DIM, T);
  // shared down: BM=128 BN=64 -> shared_out (f32)
  ffn_down<128, false><<<dim3(H_DIM / 64, T / 128), 256, 0, stream>>>(
      s_act, sw_down, (void*)shared_out, nullptr, nullptr, nullptr, IS_DIM, T);
}